// Round 5
// baseline (202.941 us; speedup 1.0000x reference)
//
#include <hip/hip_runtime.h>
#include <hip/hip_bf16.h>
#include <math.h>

// Problem sizes (fixed by reference)
static constexpr int Bn = 16, Sn = 512, Wn = 8, Dn = 768;
static constexpr int Mn_ = 2, WMn = 64;
static constexpr int Un = 32, WUn = 16;

#define INF_VAL 1e12f
#define INV_SQRT_D 0.03608439182435161f

// Output float offsets
static constexpr size_t OFF_GCN   = 0;                    // [16,512,768]
static constexpr size_t OFF_MASK  = 6291456;              // [16,512,1]
static constexpr size_t OFF_DENSE = 6299648;              // [16,512,512]
static constexpr size_t OFF_ADJ   = 10493952;             // [16,512,512]
static constexpr size_t OFF_MAIN  = 14688256;             // [16,2,768]
static constexpr size_t OFF_USER  = 14712832;             // [16,768]

// Workspace byte offsets (~35.7 MB total; ws is ~393 MB per harness fill size)
static constexpr size_t WSB_GBF     = 0;          // bf16 [8192][768]
static constexpr size_t WSB_GT      = 12582912;   // bf16 [16][768][512]
static constexpr size_t WSB_DENSEBF = 25165824;   // bf16 [8192][512]
static constexpr size_t WSB_PARTU   = 33554432;   // f32 [512][768]
static constexpr size_t WSB_PARTM   = 35127296;   // f32 [128][768]
static constexpr size_t WSB_BCAT    = 35520512;   // f32 [1536]
static constexpr size_t WSB_KBAR    = 35526656;   // f64 [768]
static constexpr size_t WSB_QBAR    = 35532800;   // f64 [768]
static constexpr size_t WSB_U       = 35538944;   // f64 [768]
static constexpr size_t WSB_V       = 35545088;   // f64 [768]
static constexpr size_t WSB_CONSTS  = 35551232;   // f64 [4]
static constexpr size_t WSB_QS      = 35551296;   // f32 [8192]
static constexpr size_t WSB_KQ      = 35584064;   // f32 [8192]
static constexpr size_t WSB_COLSUM  = 35616832;   // f32 [8192]
static constexpr size_t WSB_FLAGS   = 35649600;   // int [8192]
static constexpr size_t WSB_ROWSUM  = 35682368;   // f32 [8192]

typedef __attribute__((ext_vector_type(8))) short short8;
typedef __attribute__((ext_vector_type(4))) float f32x4;

static __device__ __forceinline__ ushort f2bf(float f) {
    union { float f; unsigned u; } v; v.f = f;
    unsigned u = v.u;
    unsigned r = (u + 0x7FFFu + ((u >> 16) & 1u)) >> 16;
    return (ushort)r;
}

static __device__ __forceinline__ void gload16(const void* g, void* lds) {
    __builtin_amdgcn_global_load_lds(
        (const __attribute__((address_space(1))) void*)g,
        (__attribute__((address_space(3))) void*)lds, 16, 0, 0);
}

static __device__ __forceinline__ void fmax4(float4& a, const float4& x) {
    a.x = fmaxf(a.x, x.x); a.y = fmaxf(a.y, x.y);
    a.z = fmaxf(a.z, x.z); a.w = fmaxf(a.w, x.w);
}

// ---------------------------------------------------------------------------
// fold1: block-range merged {kbar/qbar row sums | K/Q->bf16 convert | bcat | colsum zero}
__global__ __launch_bounds__(256)
void fold1(const float* __restrict__ K_w, const float* __restrict__ K_b,
           const float* __restrict__ Q_w, const float* __restrict__ Q_b,
           double* __restrict__ kbar, double* __restrict__ qbar,
           ushort* __restrict__ Kwb, ushort* __restrict__ Qwb,
           float* __restrict__ bcat, float* __restrict__ colsum) {
    int blk = blockIdx.x, t = threadIdx.x;
    if (blk < 192) {
        // 4 waves/block, one row per wave: kbar_r = -1e12*sum_d K_w[r,d] + K_b[r]
        int wv = t >> 6, lane = t & 63;
        int r = blk * 4 + wv;
        double sk = 0.0, sq = 0.0;
        for (int d = lane; d < Dn; d += 64) {
            sk += (double)K_w[(size_t)r * Dn + d];
            sq += (double)Q_w[(size_t)r * Dn + d];
        }
        #pragma unroll
        for (int off = 32; off > 0; off >>= 1) {
            sk += __shfl_down(sk, off, 64);
            sq += __shfl_down(sq, off, 64);
        }
        if (lane == 0) {
            kbar[r] = -1e12 * sk + (double)K_b[r];
            qbar[r] = -1e12 * sq + (double)Q_b[r];
        }
    } else if (blk < 254) {
        // bf16 convert of K_w then Q_w, grid-stride over float4s
        const int NV = Dn * Dn / 4;           // 147456 per matrix
        for (int i = (blk - 192) * 256 + t; i < 2 * NV; i += 62 * 256) {
            float4 x; ushort4 o;
            if (i < NV) x = ((const float4*)K_w)[i];
            else        x = ((const float4*)Q_w)[i - NV];
            o.x = f2bf(x.x); o.y = f2bf(x.y); o.z = f2bf(x.z); o.w = f2bf(x.w);
            if (i < NV) ((ushort4*)Kwb)[i] = o;
            else        ((ushort4*)Qwb)[i - NV] = o;
        }
    } else if (blk == 254) {
        for (int i = t; i < 1536; i += 256)
            bcat[i] = (i < Dn) ? K_b[i] : Q_b[i - Dn];
    } else {
        for (int i = t; i < Bn * Sn; i += 256) colsum[i] = 0.f;
    }
}

// fold2: blocks 0..11 = u/v direct GEMV (f64); block 12 = consts
__global__ __launch_bounds__(64)
void fold2(const float* __restrict__ K_w, const float* __restrict__ Q_w,
           const float* __restrict__ K_b, const float* __restrict__ Q_b,
           const double* __restrict__ kbar, const double* __restrict__ qbar,
           double* __restrict__ u, double* __restrict__ v,
           double* __restrict__ consts) {
    int blk = blockIdx.x, l = threadIdx.x;
    if (blk < 12) {
        __shared__ double skb[Dn], sqb[Dn];
        for (int i = l; i < Dn; i += 64) { skb[i] = kbar[i]; sqb[i] = qbar[i]; }
        __syncthreads();
        int j = blk * 64 + l;
        double su = 0.0, sv = 0.0;
        for (int e = 0; e < Dn; ++e) {
            su += (double)K_w[(size_t)e * Dn + j] * sqb[e];
            sv += (double)Q_w[(size_t)e * Dn + j] * skb[e];
        }
        u[j] = su; v[j] = sv;
    } else {
        double c0 = 0.0, c1 = 0.0, c2 = 0.0;
        for (int e = l; e < Dn; e += 64) {
            c0 += kbar[e] * (double)Q_b[e];
            c1 += kbar[e] * qbar[e];
            c2 += qbar[e] * (double)K_b[e];
        }
        #pragma unroll
        for (int off = 32; off > 0; off >>= 1) {
            c0 += __shfl_down(c0, off, 64);
            c1 += __shfl_down(c1, off, 64);
            c2 += __shfl_down(c2, off, 64);
        }
        if (l == 0) { consts[0] = c0; consts[1] = c1; consts[2] = c2; }
    }
}

// ---------------------------------------------------------------------------
// Fused adj softmax + rowsum + column partial sums (single read of adj).
__global__ __launch_bounds__(512)
void adjsm_colsum_kernel(const float* __restrict__ adj, float* __restrict__ adjsm,
                         float* __restrict__ colsum, float* __restrict__ rowsum) {
    int blk = blockIdx.x;
    int b = blk >> 5, rc = blk & 31;
    int t = threadIdx.x;
    const float* base = adj + ((size_t)b * Sn + rc * 16) * Sn;
    float* obase = adjsm + ((size_t)b * Sn + rc * 16) * Sn;
    const float EM1 = 0.36787944117144233f;   // exp(-1)
    const float EP1 = 2.718281828459045f;     // exp(+1)
    __shared__ float red[8];
    float colacc = 0.f;
    for (int r = 0; r < 16; ++r) {
        float a = base[(size_t)r * Sn + t];
        colacc += a;
        float s = a;
        #pragma unroll
        for (int off = 32; off > 0; off >>= 1) s += __shfl_down(s, off, 64);
        if ((t & 63) == 0) red[t >> 6] = s;
        __syncthreads();
        float n1 = red[0] + red[1] + red[2] + red[3]
                 + red[4] + red[5] + red[6] + red[7];
        float e1, e0;
        if (n1 > 0.f) { e1 = 1.f; e0 = EM1; } else { e1 = EP1; e0 = 1.f; }
        float denom = n1 * e1 + (512.f - n1) * e0;
        float inv = 1.f / denom;
        obase[(size_t)r * Sn + t] = (a == 1.f ? e1 : e0) * inv;
        if (t == 0) rowsum[(size_t)b * Sn + rc * 16 + r] = n1;
        __syncthreads();
    }
    atomicAdd(&colsum[(size_t)b * Sn + t], colacc);
}

// ---------------------------------------------------------------------------
// g pool: bf16 g + exact f32-row dots qs/kq (f64 accum) + row-masked flag.
__global__ __launch_bounds__(192)
void pool_g_kernel(const int* __restrict__ words, const int* __restrict__ masks,
                   const float* __restrict__ emb,
                   const double* __restrict__ u, const double* __restrict__ v,
                   const double* __restrict__ consts,
                   ushort* __restrict__ gbf, float* __restrict__ qs,
                   float* __restrict__ kq, int* __restrict__ flags) {
    int bs = blockIdx.x;
    int t = threadIdx.x;
    const int* wrow = words + (size_t)bs * Wn;
    const int* mrow = masks + (size_t)bs * Wn;
    float4 acc = make_float4(-INF_VAL, -INF_VAL, -INF_VAL, -INF_VAL);
    int nm = 0;
    #pragma unroll
    for (int w = 0; w < Wn; ++w) {
        int mk = mrow[w];
        nm += (mk != 0);
        if (mk != 0) continue;
        float4 x = ((const float4*)(emb + (size_t)wrow[w] * Dn))[t];
        fmax4(acc, x);
    }
    ushort4 o;
    o.x = f2bf(acc.x); o.y = f2bf(acc.y); o.z = f2bf(acc.z); o.w = f2bf(acc.w);
    ((ushort4*)(gbf + (size_t)bs * Dn))[t] = o;
    int j = t * 4;
    double dv = v[j] * (double)acc.x + v[j+1] * (double)acc.y
              + v[j+2] * (double)acc.z + v[j+3] * (double)acc.w;
    double du = u[j] * (double)acc.x + u[j+1] * (double)acc.y
              + u[j+2] * (double)acc.z + u[j+3] * (double)acc.w;
    #pragma unroll
    for (int off = 32; off > 0; off >>= 1) {
        dv += __shfl_down(dv, off, 64);
        du += __shfl_down(du, off, 64);
    }
    __shared__ double rr[6];
    if ((t & 63) == 0) { rr[t >> 6] = dv; rr[3 + (t >> 6)] = du; }
    __syncthreads();
    if (t == 0) {
        qs[bs] = (float)(rr[0] + rr[1] + rr[2] + consts[0]);
        kq[bs] = (float)(rr[3] + rr[4] + rr[5] + consts[2]);
        flags[bs] = (nm == Wn) ? 1 : 0;
    }
}

// merged stage1: blocks 0..127 main (16-piece chunks), 128..639 user (one user)
__global__ __launch_bounds__(192)
void pool_s1(const int* __restrict__ main_idx, const int* __restrict__ mmask,
             const int* __restrict__ user_idx, const int* __restrict__ umask,
             const float* __restrict__ emb,
             float* __restrict__ partM, float* __restrict__ partU) {
    int blk = blockIdx.x;
    int t = threadIdx.x;
    const int *irow, *mrow;
    float* dst;
    if (blk < 128) {
        int bm = blk >> 2, ch = blk & 3;
        irow = main_idx + (size_t)bm * WMn + ch * 16;
        mrow = mmask + (size_t)bm * WMn + ch * 16;
        dst = partM + (size_t)blk * Dn;
    } else {
        int bu = blk - 128;
        irow = user_idx + (size_t)bu * WUn;
        mrow = umask + (size_t)bu * WUn;
        dst = partU + (size_t)bu * Dn;
    }
    float4 acc = make_float4(-INF_VAL, -INF_VAL, -INF_VAL, -INF_VAL);
    #pragma unroll
    for (int w = 0; w < 16; ++w) {
        if (mrow[w] != 0) continue;
        float4 x = ((const float4*)(emb + (size_t)irow[w] * Dn))[t];
        fmax4(acc, x);
    }
    ((float4*)dst)[t] = acc;
}

// merged stage2 + mask: blocks 0..31 main, 32..47 user, 48..90 mask
__global__ __launch_bounds__(192)
void pool_s2m(const float* __restrict__ partM, const float* __restrict__ partU,
              float* __restrict__ outM, float* __restrict__ outU,
              const float* __restrict__ rowsum, const float* __restrict__ colsum,
              float* __restrict__ maskout) {
    int blk = blockIdx.x;
    int t = threadIdx.x;
    if (blk >= 48) {
        int i = (blk - 48) * 192 + t;
        if (i < Bn * Sn)
            maskout[i] = ((rowsum[i] + colsum[i]) == 0.f) ? 1.f : 0.f;
        return;
    }
    float4 acc = make_float4(-INF_VAL, -INF_VAL, -INF_VAL, -INF_VAL);
    float* dst;
    if (blk < 32) {
        #pragma unroll
        for (int c = 0; c < 4; ++c) {
            float4 x = ((const float4*)(partM + (size_t)(blk * 4 + c) * Dn))[t];
            fmax4(acc, x);
        }
        dst = outM + (size_t)blk * Dn;
    } else {
        int b = blk - 32;
        for (int u2 = 0; u2 < Un; ++u2) {
            float4 x = ((const float4*)(partU + (size_t)(b * Un + u2) * Dn))[t];
            fmax4(acc, x);
        }
        dst = outU + (size_t)b * Dn;
    }
    if (acc.x == -INF_VAL) acc.x = 0.f;
    if (acc.y == -INF_VAL) acc.y = 0.f;
    if (acc.z == -INF_VAL) acc.z = 0.f;
    if (acc.w == -INF_VAL) acc.w = 0.f;
    ((float4*)dst)[t] = acc;
}

// transpose bf16 g -> gT[b][d][s]
__global__ __launch_bounds__(256)
void transpose_g(const ushort* __restrict__ gbf, ushort* __restrict__ gT) {
    __shared__ ushort tile[32][33];
    int b = blockIdx.z;
    int d0 = blockIdx.x * 32, s0 = blockIdx.y * 32;
    int tx = threadIdx.x & 31, ty = threadIdx.x >> 5;
    #pragma unroll
    for (int i = 0; i < 4; ++i)
        tile[ty + i * 8][tx] = gbf[((size_t)(b * Sn + s0 + ty + i * 8)) * Dn + d0 + tx];
    __syncthreads();
    #pragma unroll
    for (int i = 0; i < 4; ++i)
        gT[((size_t)(b * Dn + d0 + ty + i * 8)) * Sn + s0 + tx] = tile[tx][ty + i * 8];
}

// ---------------------------------------------------------------------------
// bf16 MFMA GEMM: C[m][n] = sum_k A[m][k]*B[n][k] (+bias[n])
// 128x128 tile, BK=64, 256 threads = 4 waves (2x2), 16x16x32 MFMA.
// SPLITC: bf16 output split at n=768 into Cout/Cout2 (wave-uniform branch).
template<int OUT_BF16, int HASBIAS, int SPLITC>
__global__ __launch_bounds__(256)
void gemm_mfma(const ushort* __restrict__ A, const ushort* __restrict__ B,
               const float* __restrict__ bias, void* __restrict__ Cout,
               void* __restrict__ Cout2,
               int Km, int lda, int ldb, int ldc,
               long long sA, long long sB, long long sC) {
    __shared__ ushort As[128 * 64];
    __shared__ ushort Bs[128 * 64];
    const ushort* Ab = A + (size_t)blockIdx.z * sA;
    const ushort* Bb = B + (size_t)blockIdx.z * sB;
    int i0 = blockIdx.y * 128, j0 = blockIdx.x * 128;
    int tid = threadIdx.x;
    int lane = tid & 63, wv = tid >> 6;
    int wr = wv >> 1, wc = wv & 1;
    int ln15 = lane & 15, lkg = lane >> 4;
    int sub = lane >> 3;
    int c8  = lane & 7;

    f32x4 acc[4][4] = {};

    for (int k0 = 0; k0 < Km; k0 += 64) {
        #pragma unroll
        for (int it = 0; it < 4; ++it) {
            int r = it * 32 + wv * 8 + sub;
            int cc = c8 ^ (r & 7);
            ushort* dstA = As + (it * 4096 + wv * 1024) / 2;
            ushort* dstB = Bs + (it * 4096 + wv * 1024) / 2;
            gload16(Ab + (size_t)(i0 + r) * lda + k0 + cc * 8, dstA);
            gload16(Bb + (size_t)(j0 + r) * ldb + k0 + cc * 8, dstB);
        }
        __syncthreads();
        #pragma unroll
        for (int kh = 0; kh < 2; ++kh) {
            short8 af[4], bfr[4];
            int kc = kh * 4 + lkg;
            #pragma unroll
            for (int f = 0; f < 4; ++f) {
                int ra = wr * 64 + f * 16 + ln15;
                af[f] = *(const short8*)((const char*)As + ra * 128 + ((kc ^ (ra & 7)) << 4));
                int rb = wc * 64 + f * 16 + ln15;
                bfr[f] = *(const short8*)((const char*)Bs + rb * 128 + ((kc ^ (rb & 7)) << 4));
            }
            #pragma unroll
            for (int fa = 0; fa < 4; ++fa)
                #pragma unroll
                for (int fb = 0; fb < 4; ++fb)
                    acc[fa][fb] = __builtin_amdgcn_mfma_f32_16x16x32_bf16(
                        af[fa], bfr[fb], acc[fa][fb], 0, 0, 0);
        }
        __syncthreads();
    }

    #pragma unroll
    for (int fa = 0; fa < 4; ++fa) {
        #pragma unroll
        for (int fb = 0; fb < 4; ++fb) {
            int n = j0 + wc * 64 + fb * 16 + ln15;
            float bv = HASBIAS ? bias[n] : 0.0f;
            #pragma unroll
            for (int rr = 0; rr < 4; ++rr) {
                int m = i0 + wr * 64 + fa * 16 + lkg * 4 + rr;
                float val = acc[fa][fb][rr] + bv;
                if (SPLITC) {
                    ushort* dst = (n < Dn) ? (ushort*)Cout : (ushort*)Cout2;
                    int nn = (n < Dn) ? n : n - Dn;
                    dst[(size_t)m * ldc + nn] = f2bf(val);
                } else if (OUT_BF16) {
                    ((ushort*)Cout)[(size_t)blockIdx.z * sC + (size_t)m * ldc + n] = f2bf(val);
                } else {
                    ((float*)Cout)[(size_t)blockIdx.z * sC + (size_t)m * ldc + n] = val;
                }
            }
        }
    }
}

// ---------------------------------------------------------------------------
// scores fixup + row softmax. Overrides masked rows/cols with exact rank-1 values.
__global__ __launch_bounds__(256)
void softmax_fix(float* __restrict__ dense, const int* __restrict__ flags,
                 const float* __restrict__ qs, const float* __restrict__ kq,
                 const double* __restrict__ consts, ushort* __restrict__ densebf) {
    int bs = blockIdx.x;
    int b = bs >> 9;
    int t = threadIdx.x;
    float* row = dense + (size_t)bs * 512;
    int f0 = flags[(b << 9) + t];
    int f1 = flags[(b << 9) + t + 256];
    bool sm = flags[bs] != 0;
    float x0, x1;
    if (sm) {
        float c1i = (float)consts[1] * INV_SQRT_D;
        x0 = f0 ? c1i : qs[(b << 9) + t] * INV_SQRT_D;
        x1 = f1 ? c1i : qs[(b << 9) + t + 256] * INV_SQRT_D;
    } else {
        float kqi = kq[bs] * INV_SQRT_D;
        x0 = f0 ? kqi : row[t] * INV_SQRT_D;
        x1 = f1 ? kqi : row[t + 256] * INV_SQRT_D;
    }
    float m = fmaxf(x0, x1);
    #pragma unroll
    for (int off = 32; off > 0; off >>= 1) m = fmaxf(m, __shfl_down(m, off, 64));
    __shared__ float red[4];
    __shared__ float bmax, bsum;
    if ((t & 63) == 0) red[t >> 6] = m;
    __syncthreads();
    if (t == 0) bmax = fmaxf(fmaxf(red[0], red[1]), fmaxf(red[2], red[3]));
    __syncthreads();
    float mx = bmax;
    float e0 = expf(x0 - mx), e1 = expf(x1 - mx);
    float s = e0 + e1;
    #pragma unroll
    for (int off = 32; off > 0; off >>= 1) s += __shfl_down(s, off, 64);
    if ((t & 63) == 0) red[t >> 6] = s;
    __syncthreads();
    if (t == 0) bsum = red[0] + red[1] + red[2] + red[3];
    __syncthreads();
    float inv = 1.f / bsum;
    float p0 = e0 * inv, p1 = e1 * inv;
    row[t] = p0; row[t + 256] = p1;
    ushort* bro = densebf + (size_t)bs * 512;
    bro[t] = f2bf(p0); bro[t + 256] = f2bf(p1);
}

// ---------------------------------------------------------------------------
extern "C" void kernel_launch(void* const* d_in, const int* in_sizes, int n_in,
                              void* d_out, int out_size, void* d_ws, size_t ws_size,
                              hipStream_t stream) {
    const int*   words     = (const int*)d_in[0];
    const int*   masks     = (const int*)d_in[1];
    const int*   main_idx  = (const int*)d_in[2];
    const int*   main_mask = (const int*)d_in[3];
    const int*   user_idx  = (const int*)d_in[4];
    const int*   user_mask = (const int*)d_in[5];
    const float* adj       = (const float*)d_in[6];
    const float* emb       = (const float*)d_in[7];
    const float* K_w       = (const float*)d_in[8];
    const float* K_b       = (const float*)d_in[9];
    const float* Q_w       = (const float*)d_in[10];
    const float* Q_b       = (const float*)d_in[11];

    float* out = (float*)d_out;
    char*  ws8 = (char*)d_ws;

    ushort* gbf     = (ushort*)(ws8 + WSB_GBF);
    ushort* gT      = (ushort*)(ws8 + WSB_GT);
    ushort* densebf = (ushort*)(ws8 + WSB_DENSEBF);
    float*  partU   = (float*)(ws8 + WSB_PARTU);
    float*  partM   = (float*)(ws8 + WSB_PARTM);
    float*  bcat    = (float*)(ws8 + WSB_BCAT);
    double* kbar    = (double*)(ws8 + WSB_KBAR);
    double* qbar    = (double*)(ws8 + WSB_QBAR);
    double* u       = (double*)(ws8 + WSB_U);
    double* v       = (double*)(ws8 + WSB_V);
    double* consts  = (double*)(ws8 + WSB_CONSTS);
    float*  qs      = (float*)(ws8 + WSB_QS);
    float*  kq      = (float*)(ws8 + WSB_KQ);
    float*  colsum  = (float*)(ws8 + WSB_COLSUM);
    int*    flags   = (int*)(ws8 + WSB_FLAGS);
    float*  rowsum  = (float*)(ws8 + WSB_ROWSUM);

    // bf16 weights parked in DENSE region (dead until scores GEMM);
    // key/query bf16 parked in GCN region (dead until gcn GEMM)
    ushort* Kwb     = (ushort*)(out + OFF_DENSE);
    ushort* Qwb     = Kwb + (size_t)Dn * Dn;
    ushort* keybf   = (ushort*)(out + OFF_GCN);
    ushort* querybf = keybf + (size_t)Bn * Sn * Dn;
    float*  dense   = out + OFF_DENSE;

    // 1-2: weight folds + converts (merged)
    fold1<<<256, 256, 0, stream>>>(K_w, K_b, Q_w, Q_b, kbar, qbar, Kwb, Qwb, bcat, colsum);
    fold2<<<13, 64, 0, stream>>>(K_w, Q_w, K_b, Q_b, kbar, qbar, u, v, consts);

    // 3: adjacency softmax + rowsum + colsum (single adj read), direct to output
    adjsm_colsum_kernel<<<Bn * 32, 512, 0, stream>>>(adj, out + OFF_ADJ, colsum, rowsum);

    // 4-6: pools (+ node mask fused into stage2)
    pool_g_kernel<<<Bn * Sn, 192, 0, stream>>>(words, masks, emb, u, v, consts,
                                               gbf, qs, kq, flags);
    pool_s1<<<640, 192, 0, stream>>>(main_idx, main_mask, user_idx, user_mask,
                                     emb, partM, partU);
    pool_s2m<<<91, 192, 0, stream>>>(partM, partU, out + OFF_MAIN, out + OFF_USER,
                                     rowsum, colsum, out + OFF_MASK);

    // 7: transpose g for the PV GEMM
    transpose_g<<<dim3(Dn / 32, Sn / 32, Bn), 256, 0, stream>>>(gbf, gT);

    // 8: [key||query] = g @ [K_w||Q_w]^T + [K_b||Q_b]
    gemm_mfma<1, 1, 1><<<dim3(2 * Dn / 128, (Bn * Sn) / 128, 1), 256, 0, stream>>>(
        gbf, Kwb, bcat, keybf, querybf, Dn, Dn, Dn, Dn, 0, 0, 0);

    // 9: raw scores[b] = key[b] @ query[b]^T
    gemm_mfma<0, 0, 0><<<dim3(Sn / 128, Sn / 128, Bn), 256, 0, stream>>>(
        keybf, querybf, nullptr, dense, nullptr, Dn, Dn, Dn, Sn,
        (long long)Sn * Dn, (long long)Sn * Dn, (long long)Sn * Sn);

    // 10: fixup masked rows/cols + softmax; writes f32 dense + bf16 copy
    softmax_fix<<<Bn * Sn, 256, 0, stream>>>(dense, flags, qs, kq, consts, densebf);

    // 11: gcn[b] = P[b] @ g[b]
    gemm_mfma<0, 0, 0><<<dim3(Dn / 128, Sn / 128, Bn), 256, 0, stream>>>(
        densebf, gT, nullptr, out + OFF_GCN, nullptr, Sn, Sn, Sn, Dn,
        (long long)Sn * Sn, (long long)Dn * Sn, (long long)Sn * Dn);
}

// Round 6
// 170.400 us; speedup vs baseline: 1.1910x; 1.1910x over previous
//
#include <hip/hip_runtime.h>
#include <hip/hip_bf16.h>
#include <math.h>

// Problem sizes (fixed by reference)
static constexpr int Bn = 16, Sn = 512, Wn = 8, Dn = 768;
static constexpr int Mn_ = 2, WMn = 64;
static constexpr int Un = 32, WUn = 16;

#define INF_VAL 1e12f
#define INV_SQRT_D 0.03608439182435161f

// Output float offsets
static constexpr size_t OFF_GCN   = 0;                    // [16,512,768]
static constexpr size_t OFF_MASK  = 6291456;              // [16,512,1]
static constexpr size_t OFF_DENSE = 6299648;              // [16,512,512]
static constexpr size_t OFF_ADJ   = 10493952;             // [16,512,512]
static constexpr size_t OFF_MAIN  = 14688256;             // [16,2,768]
static constexpr size_t OFF_USER  = 14712832;             // [16,768]

// Workspace byte offsets (~36 MB total; ws is ~393 MB per harness fill size)
static constexpr size_t WSB_GBF     = 0;          // bf16 [8192][768]
static constexpr size_t WSB_GT      = 12582912;   // bf16 [16][768][512]
static constexpr size_t WSB_DENSEBF = 25165824;   // bf16 [8192][512]
static constexpr size_t WSB_PARTU   = 33554432;   // f32 [512][768]
static constexpr size_t WSB_PARTM   = 35127296;   // f32 [128][768]
static constexpr size_t WSB_BCAT    = 35520512;   // f32 [1536]
static constexpr size_t WSB_KBAR    = 35526656;   // f64 [768]
static constexpr size_t WSB_QBAR    = 35532800;   // f64 [768]
static constexpr size_t WSB_U       = 35538944;   // f64 [768]
static constexpr size_t WSB_V       = 35545088;   // f64 [768]
static constexpr size_t WSB_CONSTS  = 35551232;   // f64 [4]
static constexpr size_t WSB_QS      = 35551296;   // f32 [8192]
static constexpr size_t WSB_KQ      = 35584064;   // f32 [8192]
static constexpr size_t WSB_COLSUM  = 35616832;   // f32 [8192]
static constexpr size_t WSB_FLAGS   = 35649600;   // int [8192]
static constexpr size_t WSB_ROWSUM  = 35682368;   // f32 [8192]
static constexpr size_t WSB_UVU     = 35715136;   // f64 [8][768]
static constexpr size_t WSB_UVV     = 35764288;   // f64 [8][768]

typedef __attribute__((ext_vector_type(8))) short short8;
typedef __attribute__((ext_vector_type(4))) float f32x4;

static __device__ __forceinline__ ushort f2bf(float f) {
    union { float f; unsigned u; } v; v.f = f;
    unsigned u = v.u;
    unsigned r = (u + 0x7FFFu + ((u >> 16) & 1u)) >> 16;
    return (ushort)r;
}

static __device__ __forceinline__ void gload16(const void* g, void* lds) {
    __builtin_amdgcn_global_load_lds(
        (const __attribute__((address_space(1))) void*)g,
        (__attribute__((address_space(3))) void*)lds, 16, 0, 0);
}

static __device__ __forceinline__ void fmax4(float4& a, const float4& x) {
    a.x = fmaxf(a.x, x.x); a.y = fmaxf(a.y, x.y);
    a.z = fmaxf(a.z, x.z); a.w = fmaxf(a.w, x.w);
}

// ---------------------------------------------------------------------------
// fold1: block-range merged {kbar/qbar row sums | K/Q->bf16 convert | bcat | colsum zero}
__global__ __launch_bounds__(256)
void fold1(const float* __restrict__ K_w, const float* __restrict__ K_b,
           const float* __restrict__ Q_w, const float* __restrict__ Q_b,
           double* __restrict__ kbar, double* __restrict__ qbar,
           ushort* __restrict__ Kwb, ushort* __restrict__ Qwb,
           float* __restrict__ bcat, float* __restrict__ colsum) {
    int blk = blockIdx.x, t = threadIdx.x;
    if (blk < 192) {
        // 4 waves/block, one row per wave: kbar_r = -1e12*sum_d K_w[r,d] + K_b[r]
        int wv = t >> 6, lane = t & 63;
        int r = blk * 4 + wv;
        double sk = 0.0, sq = 0.0;
        for (int d = lane; d < Dn; d += 64) {
            sk += (double)K_w[(size_t)r * Dn + d];
            sq += (double)Q_w[(size_t)r * Dn + d];
        }
        #pragma unroll
        for (int off = 32; off > 0; off >>= 1) {
            sk += __shfl_down(sk, off, 64);
            sq += __shfl_down(sq, off, 64);
        }
        if (lane == 0) {
            kbar[r] = -1e12 * sk + (double)K_b[r];
            qbar[r] = -1e12 * sq + (double)Q_b[r];
        }
    } else if (blk < 254) {
        // bf16 convert of K_w then Q_w, grid-stride over float4s
        const int NV = Dn * Dn / 4;           // 147456 per matrix
        for (int i = (blk - 192) * 256 + t; i < 2 * NV; i += 62 * 256) {
            float4 x; ushort4 o;
            if (i < NV) x = ((const float4*)K_w)[i];
            else        x = ((const float4*)Q_w)[i - NV];
            o.x = f2bf(x.x); o.y = f2bf(x.y); o.z = f2bf(x.z); o.w = f2bf(x.w);
            if (i < NV) ((ushort4*)Kwb)[i] = o;
            else        ((ushort4*)Qwb)[i - NV] = o;
        }
    } else if (blk == 254) {
        for (int i = t; i < 1536; i += 256)
            bcat[i] = (i < Dn) ? K_b[i] : Q_b[i - Dn];
    } else {
        for (int i = t; i < Bn * Sn; i += 256) colsum[i] = 0.f;
    }
}

// u/v partials: u_j = sum_e K_w[e,j]*qbar_e (8-way parallel over e-chunks)
__global__ __launch_bounds__(64)
void uv_part(const float* __restrict__ K_w, const float* __restrict__ Q_w,
             const double* __restrict__ kbar, const double* __restrict__ qbar,
             double* __restrict__ uvu, double* __restrict__ uvv) {
    int j = blockIdx.x * 64 + threadIdx.x;
    int e0 = blockIdx.y * 96;
    double su = 0.0, sv = 0.0;
    for (int e = e0; e < e0 + 96; ++e) {
        su += (double)K_w[(size_t)e * Dn + j] * qbar[e];
        sv += (double)Q_w[(size_t)e * Dn + j] * kbar[e];
    }
    uvu[(size_t)blockIdx.y * Dn + j] = su;
    uvv[(size_t)blockIdx.y * Dn + j] = sv;
}

// blocks 0..11: uv reduce; block 12: consts c0,c1,c2
__global__ __launch_bounds__(64)
void uvred_consts(const double* __restrict__ uvu, const double* __restrict__ uvv,
                  const double* __restrict__ kbar, const double* __restrict__ qbar,
                  const float* __restrict__ K_b, const float* __restrict__ Q_b,
                  double* __restrict__ u, double* __restrict__ v,
                  double* __restrict__ consts) {
    int blk = blockIdx.x;
    int l = threadIdx.x;
    if (blk < 12) {
        int j = blk * 64 + l;
        double su = 0.0, sv = 0.0;
        #pragma unroll
        for (int c = 0; c < 8; ++c) {
            su += uvu[(size_t)c * Dn + j];
            sv += uvv[(size_t)c * Dn + j];
        }
        u[j] = su; v[j] = sv;
    } else {
        double c0 = 0.0, c1 = 0.0, c2 = 0.0;
        for (int e = l; e < Dn; e += 64) {
            c0 += kbar[e] * (double)Q_b[e];
            c1 += kbar[e] * qbar[e];
            c2 += qbar[e] * (double)K_b[e];
        }
        #pragma unroll
        for (int off = 32; off > 0; off >>= 1) {
            c0 += __shfl_down(c0, off, 64);
            c1 += __shfl_down(c1, off, 64);
            c2 += __shfl_down(c2, off, 64);
        }
        if (l == 0) { consts[0] = c0; consts[1] = c1; consts[2] = c2; }
    }
}

// ---------------------------------------------------------------------------
// Fused adj softmax + rowsum + column partial sums (single read of adj).
__global__ __launch_bounds__(512)
void adjsm_colsum_kernel(const float* __restrict__ adj, float* __restrict__ adjsm,
                         float* __restrict__ colsum, float* __restrict__ rowsum) {
    int blk = blockIdx.x;
    int b = blk >> 5, rc = blk & 31;
    int t = threadIdx.x;
    const float* base = adj + ((size_t)b * Sn + rc * 16) * Sn;
    float* obase = adjsm + ((size_t)b * Sn + rc * 16) * Sn;
    const float EM1 = 0.36787944117144233f;   // exp(-1)
    const float EP1 = 2.718281828459045f;     // exp(+1)
    __shared__ float red[8];
    float colacc = 0.f;
    for (int r = 0; r < 16; ++r) {
        float a = base[(size_t)r * Sn + t];
        colacc += a;
        float s = a;
        #pragma unroll
        for (int off = 32; off > 0; off >>= 1) s += __shfl_down(s, off, 64);
        if ((t & 63) == 0) red[t >> 6] = s;
        __syncthreads();
        float n1 = red[0] + red[1] + red[2] + red[3]
                 + red[4] + red[5] + red[6] + red[7];
        float e1, e0;
        if (n1 > 0.f) { e1 = 1.f; e0 = EM1; } else { e1 = EP1; e0 = 1.f; }
        float denom = n1 * e1 + (512.f - n1) * e0;
        float inv = 1.f / denom;
        obase[(size_t)r * Sn + t] = (a == 1.f ? e1 : e0) * inv;
        if (t == 0) rowsum[(size_t)b * Sn + rc * 16 + r] = n1;
        __syncthreads();
    }
    atomicAdd(&colsum[(size_t)b * Sn + t], colacc);
}

// ---------------------------------------------------------------------------
// g pool: bf16 g + exact f32-row dots qs/kq (f64 accum) + row-masked flag.
__global__ __launch_bounds__(192)
void pool_g_kernel(const int* __restrict__ words, const int* __restrict__ masks,
                   const float* __restrict__ emb,
                   const double* __restrict__ u, const double* __restrict__ v,
                   const double* __restrict__ consts,
                   ushort* __restrict__ gbf, float* __restrict__ qs,
                   float* __restrict__ kq, int* __restrict__ flags) {
    int bs = blockIdx.x;
    int t = threadIdx.x;
    const int* wrow = words + (size_t)bs * Wn;
    const int* mrow = masks + (size_t)bs * Wn;
    float4 acc = make_float4(-INF_VAL, -INF_VAL, -INF_VAL, -INF_VAL);
    int nm = 0;
    #pragma unroll
    for (int w = 0; w < Wn; ++w) {
        int mk = mrow[w];
        nm += (mk != 0);
        if (mk != 0) continue;
        float4 x = ((const float4*)(emb + (size_t)wrow[w] * Dn))[t];
        fmax4(acc, x);
    }
    ushort4 o;
    o.x = f2bf(acc.x); o.y = f2bf(acc.y); o.z = f2bf(acc.z); o.w = f2bf(acc.w);
    ((ushort4*)(gbf + (size_t)bs * Dn))[t] = o;
    int j = t * 4;
    double dv = v[j] * (double)acc.x + v[j+1] * (double)acc.y
              + v[j+2] * (double)acc.z + v[j+3] * (double)acc.w;
    double du = u[j] * (double)acc.x + u[j+1] * (double)acc.y
              + u[j+2] * (double)acc.z + u[j+3] * (double)acc.w;
    #pragma unroll
    for (int off = 32; off > 0; off >>= 1) {
        dv += __shfl_down(dv, off, 64);
        du += __shfl_down(du, off, 64);
    }
    __shared__ double rr[6];
    if ((t & 63) == 0) { rr[t >> 6] = dv; rr[3 + (t >> 6)] = du; }
    __syncthreads();
    if (t == 0) {
        qs[bs] = (float)(rr[0] + rr[1] + rr[2] + consts[0]);
        kq[bs] = (float)(rr[3] + rr[4] + rr[5] + consts[2]);
        flags[bs] = (nm == Wn) ? 1 : 0;
    }
}

// merged stage1: blocks 0..127 main (16-piece chunks), 128..639 user (one user)
__global__ __launch_bounds__(192)
void pool_s1(const int* __restrict__ main_idx, const int* __restrict__ mmask,
             const int* __restrict__ user_idx, const int* __restrict__ umask,
             const float* __restrict__ emb,
             float* __restrict__ partM, float* __restrict__ partU) {
    int blk = blockIdx.x;
    int t = threadIdx.x;
    const int *irow, *mrow;
    float* dst;
    if (blk < 128) {
        int bm = blk >> 2, ch = blk & 3;
        irow = main_idx + (size_t)bm * WMn + ch * 16;
        mrow = mmask + (size_t)bm * WMn + ch * 16;
        dst = partM + (size_t)blk * Dn;
    } else {
        int bu = blk - 128;
        irow = user_idx + (size_t)bu * WUn;
        mrow = umask + (size_t)bu * WUn;
        dst = partU + (size_t)bu * Dn;
    }
    float4 acc = make_float4(-INF_VAL, -INF_VAL, -INF_VAL, -INF_VAL);
    #pragma unroll
    for (int w = 0; w < 16; ++w) {
        if (mrow[w] != 0) continue;
        float4 x = ((const float4*)(emb + (size_t)irow[w] * Dn))[t];
        fmax4(acc, x);
    }
    ((float4*)dst)[t] = acc;
}

// merged stage2 + mask: blocks 0..31 main, 32..47 user, 48..90 mask
__global__ __launch_bounds__(192)
void pool_s2m(const float* __restrict__ partM, const float* __restrict__ partU,
              float* __restrict__ outM, float* __restrict__ outU,
              const float* __restrict__ rowsum, const float* __restrict__ colsum,
              float* __restrict__ maskout) {
    int blk = blockIdx.x;
    int t = threadIdx.x;
    if (blk >= 48) {
        int i = (blk - 48) * 192 + t;
        if (i < Bn * Sn)
            maskout[i] = ((rowsum[i] + colsum[i]) == 0.f) ? 1.f : 0.f;
        return;
    }
    float4 acc = make_float4(-INF_VAL, -INF_VAL, -INF_VAL, -INF_VAL);
    float* dst;
    if (blk < 32) {
        #pragma unroll
        for (int c = 0; c < 4; ++c) {
            float4 x = ((const float4*)(partM + (size_t)(blk * 4 + c) * Dn))[t];
            fmax4(acc, x);
        }
        dst = outM + (size_t)blk * Dn;
    } else {
        int b = blk - 32;
        for (int u2 = 0; u2 < Un; ++u2) {
            float4 x = ((const float4*)(partU + (size_t)(b * Un + u2) * Dn))[t];
            fmax4(acc, x);
        }
        dst = outU + (size_t)b * Dn;
    }
    if (acc.x == -INF_VAL) acc.x = 0.f;
    if (acc.y == -INF_VAL) acc.y = 0.f;
    if (acc.z == -INF_VAL) acc.z = 0.f;
    if (acc.w == -INF_VAL) acc.w = 0.f;
    ((float4*)dst)[t] = acc;
}

// transpose bf16 g -> gT[b][d][s]
__global__ __launch_bounds__(256)
void transpose_g(const ushort* __restrict__ gbf, ushort* __restrict__ gT) {
    __shared__ ushort tile[32][33];
    int b = blockIdx.z;
    int d0 = blockIdx.x * 32, s0 = blockIdx.y * 32;
    int tx = threadIdx.x & 31, ty = threadIdx.x >> 5;
    #pragma unroll
    for (int i = 0; i < 4; ++i)
        tile[ty + i * 8][tx] = gbf[((size_t)(b * Sn + s0 + ty + i * 8)) * Dn + d0 + tx];
    __syncthreads();
    #pragma unroll
    for (int i = 0; i < 4; ++i)
        gT[((size_t)(b * Dn + d0 + ty + i * 8)) * Sn + s0 + tx] = tile[tx][ty + i * 8];
}

// ---------------------------------------------------------------------------
// bf16 MFMA GEMM: C[m][n] = sum_k A[m][k]*B[n][k] (+bias[n])
// 128x128 tile, BK=64, 256 threads = 4 waves (2x2), 16x16x32 MFMA.
// SPLITC: bf16 output split at n=768 into Cout/Cout2 (wave-uniform branch).
template<int OUT_BF16, int HASBIAS, int SPLITC>
__global__ __launch_bounds__(256)
void gemm_mfma(const ushort* __restrict__ A, const ushort* __restrict__ B,
               const float* __restrict__ bias, void* __restrict__ Cout,
               void* __restrict__ Cout2,
               int Km, int lda, int ldb, int ldc,
               long long sA, long long sB, long long sC) {
    __shared__ ushort As[128 * 64];
    __shared__ ushort Bs[128 * 64];
    const ushort* Ab = A + (size_t)blockIdx.z * sA;
    const ushort* Bb = B + (size_t)blockIdx.z * sB;
    int i0 = blockIdx.y * 128, j0 = blockIdx.x * 128;
    int tid = threadIdx.x;
    int lane = tid & 63, wv = tid >> 6;
    int wr = wv >> 1, wc = wv & 1;
    int ln15 = lane & 15, lkg = lane >> 4;
    int sub = lane >> 3;
    int c8  = lane & 7;

    f32x4 acc[4][4] = {};

    for (int k0 = 0; k0 < Km; k0 += 64) {
        #pragma unroll
        for (int it = 0; it < 4; ++it) {
            int r = it * 32 + wv * 8 + sub;
            int cc = c8 ^ (r & 7);
            ushort* dstA = As + (it * 4096 + wv * 1024) / 2;
            ushort* dstB = Bs + (it * 4096 + wv * 1024) / 2;
            gload16(Ab + (size_t)(i0 + r) * lda + k0 + cc * 8, dstA);
            gload16(Bb + (size_t)(j0 + r) * ldb + k0 + cc * 8, dstB);
        }
        __syncthreads();
        #pragma unroll
        for (int kh = 0; kh < 2; ++kh) {
            short8 af[4], bfr[4];
            int kc = kh * 4 + lkg;
            #pragma unroll
            for (int f = 0; f < 4; ++f) {
                int ra = wr * 64 + f * 16 + ln15;
                af[f] = *(const short8*)((const char*)As + ra * 128 + ((kc ^ (ra & 7)) << 4));
                int rb = wc * 64 + f * 16 + ln15;
                bfr[f] = *(const short8*)((const char*)Bs + rb * 128 + ((kc ^ (rb & 7)) << 4));
            }
            #pragma unroll
            for (int fa = 0; fa < 4; ++fa)
                #pragma unroll
                for (int fb = 0; fb < 4; ++fb)
                    acc[fa][fb] = __builtin_amdgcn_mfma_f32_16x16x32_bf16(
                        af[fa], bfr[fb], acc[fa][fb], 0, 0, 0);
        }
        __syncthreads();
    }

    #pragma unroll
    for (int fa = 0; fa < 4; ++fa) {
        #pragma unroll
        for (int fb = 0; fb < 4; ++fb) {
            int n = j0 + wc * 64 + fb * 16 + ln15;
            float bv = HASBIAS ? bias[n] : 0.0f;
            #pragma unroll
            for (int rr = 0; rr < 4; ++rr) {
                int m = i0 + wr * 64 + fa * 16 + lkg * 4 + rr;
                float val = acc[fa][fb][rr] + bv;
                if (SPLITC) {
                    ushort* dst = (n < Dn) ? (ushort*)Cout : (ushort*)Cout2;
                    int nn = (n < Dn) ? n : n - Dn;
                    dst[(size_t)m * ldc + nn] = f2bf(val);
                } else if (OUT_BF16) {
                    ((ushort*)Cout)[(size_t)blockIdx.z * sC + (size_t)m * ldc + n] = f2bf(val);
                } else {
                    ((float*)Cout)[(size_t)blockIdx.z * sC + (size_t)m * ldc + n] = val;
                }
            }
        }
    }
}

// ---------------------------------------------------------------------------
// scores fixup + row softmax. Overrides masked rows/cols with exact rank-1 values.
__global__ __launch_bounds__(256)
void softmax_fix(float* __restrict__ dense, const int* __restrict__ flags,
                 const float* __restrict__ qs, const float* __restrict__ kq,
                 const double* __restrict__ consts, ushort* __restrict__ densebf) {
    int bs = blockIdx.x;
    int b = bs >> 9;
    int t = threadIdx.x;
    float* row = dense + (size_t)bs * 512;
    int f0 = flags[(b << 9) + t];
    int f1 = flags[(b << 9) + t + 256];
    bool sm = flags[bs] != 0;
    float x0, x1;
    if (sm) {
        float c1i = (float)consts[1] * INV_SQRT_D;
        x0 = f0 ? c1i : qs[(b << 9) + t] * INV_SQRT_D;
        x1 = f1 ? c1i : qs[(b << 9) + t + 256] * INV_SQRT_D;
    } else {
        float kqi = kq[bs] * INV_SQRT_D;
        x0 = f0 ? kqi : row[t] * INV_SQRT_D;
        x1 = f1 ? kqi : row[t + 256] * INV_SQRT_D;
    }
    float m = fmaxf(x0, x1);
    #pragma unroll
    for (int off = 32; off > 0; off >>= 1) m = fmaxf(m, __shfl_down(m, off, 64));
    __shared__ float red[4];
    __shared__ float bmax, bsum;
    if ((t & 63) == 0) red[t >> 6] = m;
    __syncthreads();
    if (t == 0) bmax = fmaxf(fmaxf(red[0], red[1]), fmaxf(red[2], red[3]));
    __syncthreads();
    float mx = bmax;
    float e0 = expf(x0 - mx), e1 = expf(x1 - mx);
    float s = e0 + e1;
    #pragma unroll
    for (int off = 32; off > 0; off >>= 1) s += __shfl_down(s, off, 64);
    if ((t & 63) == 0) red[t >> 6] = s;
    __syncthreads();
    if (t == 0) bsum = red[0] + red[1] + red[2] + red[3];
    __syncthreads();
    float inv = 1.f / bsum;
    float p0 = e0 * inv, p1 = e1 * inv;
    row[t] = p0; row[t + 256] = p1;
    ushort* bro = densebf + (size_t)bs * 512;
    bro[t] = f2bf(p0); bro[t + 256] = f2bf(p1);
}

// ---------------------------------------------------------------------------
extern "C" void kernel_launch(void* const* d_in, const int* in_sizes, int n_in,
                              void* d_out, int out_size, void* d_ws, size_t ws_size,
                              hipStream_t stream) {
    const int*   words     = (const int*)d_in[0];
    const int*   masks     = (const int*)d_in[1];
    const int*   main_idx  = (const int*)d_in[2];
    const int*   main_mask = (const int*)d_in[3];
    const int*   user_idx  = (const int*)d_in[4];
    const int*   user_mask = (const int*)d_in[5];
    const float* adj       = (const float*)d_in[6];
    const float* emb       = (const float*)d_in[7];
    const float* K_w       = (const float*)d_in[8];
    const float* K_b       = (const float*)d_in[9];
    const float* Q_w       = (const float*)d_in[10];
    const float* Q_b       = (const float*)d_in[11];

    float* out = (float*)d_out;
    char*  ws8 = (char*)d_ws;

    ushort* gbf     = (ushort*)(ws8 + WSB_GBF);
    ushort* gT      = (ushort*)(ws8 + WSB_GT);
    ushort* densebf = (ushort*)(ws8 + WSB_DENSEBF);
    float*  partU   = (float*)(ws8 + WSB_PARTU);
    float*  partM   = (float*)(ws8 + WSB_PARTM);
    float*  bcat    = (float*)(ws8 + WSB_BCAT);
    double* kbar    = (double*)(ws8 + WSB_KBAR);
    double* qbar    = (double*)(ws8 + WSB_QBAR);
    double* u       = (double*)(ws8 + WSB_U);
    double* v       = (double*)(ws8 + WSB_V);
    double* consts  = (double*)(ws8 + WSB_CONSTS);
    float*  qs      = (float*)(ws8 + WSB_QS);
    float*  kq      = (float*)(ws8 + WSB_KQ);
    float*  colsum  = (float*)(ws8 + WSB_COLSUM);
    int*    flags   = (int*)(ws8 + WSB_FLAGS);
    float*  rowsum  = (float*)(ws8 + WSB_ROWSUM);
    double* uvu     = (double*)(ws8 + WSB_UVU);
    double* uvv     = (double*)(ws8 + WSB_UVV);

    // bf16 weights parked in DENSE region (dead until scores GEMM);
    // key/query bf16 parked in GCN region (dead until gcn GEMM)
    ushort* Kwb     = (ushort*)(out + OFF_DENSE);
    ushort* Qwb     = Kwb + (size_t)Dn * Dn;
    ushort* keybf   = (ushort*)(out + OFF_GCN);
    ushort* querybf = keybf + (size_t)Bn * Sn * Dn;
    float*  dense   = out + OFF_DENSE;

    // 1-3: weight folds + converts (parallel u/v partials, then reduce+consts)
    fold1<<<256, 256, 0, stream>>>(K_w, K_b, Q_w, Q_b, kbar, qbar, Kwb, Qwb, bcat, colsum);
    uv_part<<<dim3(Dn / 64, 8), 64, 0, stream>>>(K_w, Q_w, kbar, qbar, uvu, uvv);
    uvred_consts<<<13, 64, 0, stream>>>(uvu, uvv, kbar, qbar, K_b, Q_b, u, v, consts);

    // 4: adjacency softmax + rowsum + colsum (single adj read), direct to output
    adjsm_colsum_kernel<<<Bn * 32, 512, 0, stream>>>(adj, out + OFF_ADJ, colsum, rowsum);

    // 5-7: pools (+ node mask fused into stage2)
    pool_g_kernel<<<Bn * Sn, 192, 0, stream>>>(words, masks, emb, u, v, consts,
                                               gbf, qs, kq, flags);
    pool_s1<<<640, 192, 0, stream>>>(main_idx, main_mask, user_idx, user_mask,
                                     emb, partM, partU);
    pool_s2m<<<91, 192, 0, stream>>>(partM, partU, out + OFF_MAIN, out + OFF_USER,
                                     rowsum, colsum, out + OFF_MASK);

    // 8: transpose g for the PV GEMM
    transpose_g<<<dim3(Dn / 32, Sn / 32, Bn), 256, 0, stream>>>(gbf, gT);

    // 9: [key||query] = g @ [K_w||Q_w]^T + [K_b||Q_b]
    gemm_mfma<1, 1, 1><<<dim3(2 * Dn / 128, (Bn * Sn) / 128, 1), 256, 0, stream>>>(
        gbf, Kwb, bcat, keybf, querybf, Dn, Dn, Dn, Dn, 0, 0, 0);

    // 10: raw scores[b] = key[b] @ query[b]^T
    gemm_mfma<0, 0, 0><<<dim3(Sn / 128, Sn / 128, Bn), 256, 0, stream>>>(
        keybf, querybf, nullptr, dense, nullptr, Dn, Dn, Dn, Sn,
        (long long)Sn * Dn, (long long)Sn * Dn, (long long)Sn * Sn);

    // 11: fixup masked rows/cols + softmax; writes f32 dense + bf16 copy
    softmax_fix<<<Bn * Sn, 256, 0, stream>>>(dense, flags, qs, kq, consts, densebf);

    // 12: gcn[b] = P[b] @ g[b]
    gemm_mfma<0, 0, 0><<<dim3(Dn / 128, Sn / 128, Bn), 256, 0, stream>>>(
        densebf, gT, nullptr, out + OFF_GCN, nullptr, Sn, Sn, Sn, Dn,
        (long long)Sn * Sn, (long long)Dn * Sn, (long long)Sn * Dn);
}